// Round 5
// baseline (368.644 us; speedup 1.0000x reference)
//
#include <hip/hip_runtime.h>
#include <cstdint>
#include <cstddef>

// ---------------------------------------------------------------- types
typedef float  f32x4 __attribute__((ext_vector_type(4)));
typedef short  s16x8 __attribute__((ext_vector_type(8)));
typedef __bf16 bf16x8 __attribute__((ext_vector_type(8)));

static __device__ __forceinline__ f32x4 mfma16(s16x8 a, s16x8 b, f32x4 c) {
    return __builtin_amdgcn_mfma_f32_16x16x32_bf16(
        __builtin_bit_cast(bf16x8, a), __builtin_bit_cast(bf16x8, b), c, 0, 0, 0);
}

static __device__ __forceinline__ unsigned short f2bf(float f) {
    unsigned int u = __builtin_bit_cast(unsigned int, f);
    u = (u + 0x7fffu + ((u >> 16) & 1u)) >> 16;
    return (unsigned short)u;
}
static __device__ __forceinline__ float bf2f(unsigned short h) {
    unsigned int u = ((unsigned int)h) << 16;
    return __builtin_bit_cast(float, u);
}

#define COEF 0.08838834764831845f

// ---------------------------------------------------------------- prep (round-1 verbatim)
__global__ __launch_bounds__(256) void k_prep(
    const float* __restrict__ Wkey, const float* __restrict__ Wval,
    const float* __restrict__ vloc, const float* __restrict__ vlscl, const float* __restrict__ nview,
    const float* __restrict__ aoloc, const float* __restrict__ aoscl, const float* __restrict__ nobj,
    const float* __restrict__ abloc, const float* __restrict__ abscl, const float* __restrict__ nbck,
    unsigned short* __restrict__ Wt, unsigned short* __restrict__ qbf,
    float* __restrict__ sview, float* __restrict__ sattr)
{
    int blk = blockIdx.x, t = threadIdx.x;
    if (blk < 320) {
        float v = (blk < 128) ? Wkey[t * 128 + blk] : Wval[t * 192 + (blk - 128)];
        Wt[blk * 256 + t] = f2bf(v);
    } else if (blk < 356) {
        int g = (blk - 320) * 256 + t;
        if (g < 2048) {
            int d = g & 63;
            sview[g] = vloc[d] + __expf(vlscl[d]) * nview[g];
        } else {
            int u = g - 2048;               // [b][s][128]
            int b = u / 896, r = u % 896, s = r >> 7, d = r & 127;
            float val;
            if (s < 6) val = aoloc[d] + __expf(aoscl[d]) * nobj[(b * 6 + s) * 128 + d];
            else       val = abloc[d] + __expf(abscl[d]) * nbck[b * 128 + d];
            sattr[u] = val;
        }
    } else {
        for (int e = (blk - 356) * 256 + t; e < 32 * 9 * 128; e += 1024) {
            int bv = e / 1152, r = e % 1152, s = 7 + r / 128, k = r & 127;
            qbf[(bv * 16 + s) * 128 + k] = 0;
        }
    }
}

// ---------------------------------------------------------------- phase A (round-1 verbatim, measured 110.8 us)
__global__ __launch_bounds__(256) void k_lnkv(
    const float* __restrict__ x, const float* __restrict__ lng, const float* __restrict__ lnb,
    const unsigned short* __restrict__ Wt, unsigned short* __restrict__ xkv)
{
    __shared__ unsigned short lds[64 * 320];        // 40 KB
    const int t = threadIdx.x, wave = t >> 6, lane = t & 63;
    const int l15 = lane & 15, lg = lane >> 4;
    const long rowbase = (long)blockIdx.x * 64;

    float4 gv = *(const float4*)(lng + lane * 4);
    float4 bv = *(const float4*)(lnb + lane * 4);
    for (int r = 0; r < 16; ++r) {
        int row = wave * 16 + r;
        float4 xv = *(const float4*)(x + (rowbase + row) * 256 + lane * 4);
        float s1 = xv.x + xv.y + xv.z + xv.w;
        float s2 = xv.x * xv.x + xv.y * xv.y + xv.z * xv.z + xv.w * xv.w;
        #pragma unroll
        for (int o = 32; o > 0; o >>= 1) { s1 += __shfl_xor(s1, o); s2 += __shfl_xor(s2, o); }
        float mean = s1 * (1.f / 256.f);
        float var  = s2 * (1.f / 256.f) - mean * mean;
        float rstd = rsqrtf(var + 1e-5f);
        float y0 = (xv.x - mean) * rstd * gv.x + bv.x;
        float y1 = (xv.y - mean) * rstd * gv.y + bv.y;
        float y2 = (xv.z - mean) * rstd * gv.z + bv.z;
        float y3 = (xv.w - mean) * rstd * gv.w + bv.w;
        unsigned int u0 = (unsigned)f2bf(y0) | ((unsigned)f2bf(y1) << 16);
        unsigned int u1 = (unsigned)f2bf(y2) | ((unsigned)f2bf(y3) << 16);
        int off = row * 512 + ((lane * 8) ^ ((row & 7) << 4));
        *(uint2*)((char*)lds + off) = make_uint2(u0, u1);
    }
    __syncthreads();

    f32x4 acc[4][5];
    #pragma unroll
    for (int mt = 0; mt < 4; ++mt)
        #pragma unroll
        for (int nt = 0; nt < 5; ++nt) acc[mt][nt] = (f32x4){0.f, 0.f, 0.f, 0.f};

    const int nb = wave * 80;
    #pragma unroll
    for (int kk = 0; kk < 8; ++kk) {
        s16x8 a[4], b[5];
        #pragma unroll
        for (int mt = 0; mt < 4; ++mt) {
            int row = mt * 16 + l15;
            int off = row * 512 + ((kk * 64 + lg * 16) ^ ((row & 7) << 4));
            a[mt] = *(const s16x8*)((char*)lds + off);
        }
        #pragma unroll
        for (int nt = 0; nt < 5; ++nt) {
            int col = nb + nt * 16 + l15;
            b[nt] = *(const s16x8*)(Wt + col * 256 + kk * 32 + lg * 8);
        }
        #pragma unroll
        for (int mt = 0; mt < 4; ++mt)
            #pragma unroll
            for (int nt = 0; nt < 5; ++nt)
                acc[mt][nt] = mfma16(a[mt], b[nt], acc[mt][nt]);
    }
    __syncthreads();

    #pragma unroll
    for (int mt = 0; mt < 4; ++mt)
        #pragma unroll
        for (int nt = 0; nt < 5; ++nt)
            #pragma unroll
            for (int rg = 0; rg < 4; ++rg) {
                int row = mt * 16 + lg * 4 + rg;
                int col = nb + nt * 16 + l15;
                lds[row * 320 + col] = f2bf(acc[mt][nt][rg]);
            }
    __syncthreads();
    const uint4* src = (const uint4*)lds;
    uint4* dst = (uint4*)(xkv + rowbase * 320);
    #pragma unroll
    for (int j = 0; j < 10; ++j) dst[j * 256 + t] = src[j * 256 + t];
}

// ---------------------------------------------------------------- per-iter: q (round-1 verbatim)
__global__ __launch_bounds__(192) void k_qry(
    const float* __restrict__ sview, const float* __restrict__ sattr,
    const float* __restrict__ lng, const float* __restrict__ lnb,
    const float* __restrict__ Wq, float* __restrict__ full, unsigned short* __restrict__ qbf)
{
    int row = blockIdx.x;                  // bv*7 + s
    int bv = row / 7, s = row % 7, b = bv >> 2;
    int j = threadIdx.x;
    __shared__ float fr[192];
    __shared__ float red[8];
    float v = (j < 64) ? sview[bv * 64 + j] : sattr[(b * 7 + s) * 128 + (j - 64)];
    full[row * 192 + j] = v;
    float s1 = v, s2 = v * v;
    #pragma unroll
    for (int o = 32; o > 0; o >>= 1) { s1 += __shfl_xor(s1, o); s2 += __shfl_xor(s2, o); }
    int wave = j >> 6, lane = j & 63;
    if (lane == 0) { red[wave] = s1; red[4 + wave] = s2; }
    __syncthreads();
    float ts = red[0] + red[1] + red[2], ts2 = red[4] + red[5] + red[6];
    float mean = ts * (1.f / 192.f);
    float var  = ts2 * (1.f / 192.f) - mean * mean;
    float rstd = rsqrtf(var + 1e-5f);
    fr[j] = (v - mean) * rstd * lng[j] + lnb[j];
    __syncthreads();
    if (j < 128) {
        float acc = 0.f;
        for (int k = 0; k < 192; ++k) acc += fr[k] * Wq[k * 128 + j];
        qbf[(bv * 16 + s) * 128 + j] = f2bf(acc * COEF);
    }
}

// ---------------------------------------------------------------- per-iter: fused attn + updates (r2 k_att verbatim)
__global__ __launch_bounds__(256) void k_att(
    const unsigned short* __restrict__ qbf, const unsigned short* __restrict__ xkv,
    float* __restrict__ pU, float* __restrict__ pZ)
{
    int blk = blockIdx.x;                  // 512 = 32 bv * 16 chunks
    int bv = blk >> 4, chunk = blk & 15;
    int n0 = chunk * 256;
    int t = threadIdx.x, wave = t >> 6, lane = t & 63;
    int l15 = lane & 15, lg = lane >> 4;
    __shared__ float wl[256 * 8];

    s16x8 aq[4];
    const unsigned short* qrow = qbf + (bv * 16 + l15) * 128 + lg * 8;
    #pragma unroll
    for (int kk = 0; kk < 4; ++kk) aq[kk] = *(const s16x8*)(qrow + kk * 32);

    #pragma unroll
    for (int tt = 0; tt < 4; ++tt) {
        int nloc = (wave * 4 + tt) * 16;
        const unsigned short* xr = xkv + ((long)(bv * 4096 + n0 + nloc + l15)) * 320 + lg * 8;
        f32x4 acc = (f32x4){0.f, 0.f, 0.f, 0.f};
        #pragma unroll
        for (int kk = 0; kk < 4; ++kk) {
            s16x8 bfr = *(const s16x8*)(xr + kk * 32);
            acc = mfma16(aq[kk], bfr, acc);
        }
        float o0 = __shfl_xor(acc[0], 16), o1 = __shfl_xor(acc[1], 16);
        float o2 = __shfl_xor(acc[2], 16), o3 = __shfl_xor(acc[3], 16);
        bool hi = (lg & 1);
        float v0 = hi ? o0 : acc[0], v1 = hi ? o1 : acc[1];
        float v2 = hi ? o2 : acc[2], v3 = hi ? o3 : acc[3];
        float v4 = hi ? acc[0] : o0, v5 = hi ? acc[1] : o1, v6 = hi ? acc[2] : o2;
        float m = fmaxf(fmaxf(fmaxf(v0, v1), fmaxf(v2, v3)), fmaxf(fmaxf(v4, v5), v6));
        float e0 = __expf(v0 - m), e1 = __expf(v1 - m), e2 = __expf(v2 - m), e3 = __expf(v3 - m);
        float e4 = __expf(v4 - m), e5 = __expf(v5 - m), e6 = __expf(v6 - m);
        float inv = 1.f / (e0 + e1 + e2 + e3 + e4 + e5 + e6);
        if (lg < 2) {
            int n = nloc + l15;
            float4 out = (lg == 0) ? make_float4(e0 * inv, e1 * inv, e2 * inv, e3 * inv)
                                   : make_float4(e4 * inv, e5 * inv, e6 * inv, 0.f);
            *(float4*)(wl + n * 8 + lg * 4) = out;
        }
    }
    __syncthreads();

    // ---- pZ: 7 slots x 32-lane partial reduce
    if (t < 224) {
        int s = t >> 5, part = t & 31;
        float z = 0.f;
        #pragma unroll
        for (int k = 0; k < 8; ++k) z += wl[(part + 32 * k) * 8 + s];
        #pragma unroll
        for (int o = 16; o > 0; o >>= 1) z += __shfl_xor(z, o);
        if (part == 0) pZ[(bv * 16 + chunk) * 7 + s] = z;
    }

    // ---- updates partials: thread t = value column
    if (t < 192) {
        float a0 = 0, a1 = 0, a2 = 0, a3 = 0, a4 = 0, a5 = 0, a6 = 0;
        const unsigned short* xp = xkv + ((long)(bv * 4096 + n0)) * 320 + 128 + t;
        #pragma unroll 2
        for (int n = 0; n < 256; ++n) {
            float xv = bf2f(xp[n * 320]);
            float4 wa = *(const float4*)(wl + n * 8);
            float4 wb = *(const float4*)(wl + n * 8 + 4);
            a0 += wa.x * xv; a1 += wa.y * xv; a2 += wa.z * xv; a3 += wa.w * xv;
            a4 += wb.x * xv; a5 += wb.y * xv; a6 += wb.z * xv;
        }
        long base = (((long)bv * 16 + chunk) * 7) * 192 + t;
        pU[base + 0 * 192] = a0; pU[base + 1 * 192] = a1; pU[base + 2 * 192] = a2;
        pU[base + 3 * 192] = a3; pU[base + 4 * 192] = a4; pU[base + 5 * 192] = a5;
        pU[base + 6 * 192] = a6;
    }
}

// ---------------------------------------------------------------- per-iter: GRU+MLP (round-1 verbatim, f32 weights)
__global__ __launch_bounds__(192) void k_gru(
    const float* __restrict__ pU, const float* __restrict__ pZ, const float* __restrict__ full,
    const float* __restrict__ Wi, const float* __restrict__ Wh,
    const float* __restrict__ bi, const float* __restrict__ bh,
    const float* __restrict__ lng, const float* __restrict__ lnb,
    const float* __restrict__ W1, const float* __restrict__ b1,
    const float* __restrict__ W2, const float* __restrict__ b2,
    float* __restrict__ fnew)
{
    int row = blockIdx.x;                  // bv*7 + s
    int bv = row / 7, s = row % 7;
    int j = threadIdx.x;
    __shared__ float u[192], h[192], lnm[192], h1[256], red[8];

    float us = 0.f;
    #pragma unroll
    for (int c = 0; c < 16; ++c) us += pU[(((long)bv * 16 + c) * 7 + s) * 192 + j];
    float Z = 0.f;
    #pragma unroll
    for (int c = 0; c < 16; ++c) Z += pZ[(bv * 16 + c) * 7 + s];
    us /= Z;
    u[j] = us;
    float hv = full[row * 192 + j];
    h[j] = hv;
    __syncthreads();

    float gr = 0, gz = 0, gn = 0, hr = 0, hz = 0, hn = 0;
    for (int k = 0; k < 192; ++k) {
        float uk = u[k], hk = h[k];
        const float* wik = Wi + k * 576 + j;
        const float* whk = Wh + k * 576 + j;
        gr += uk * wik[0];   gz += uk * wik[192]; gn += uk * wik[384];
        hr += hk * whk[0];   hz += hk * whk[192]; hn += hk * whk[384];
    }
    gr += bi[j]; gz += bi[192 + j]; gn += bi[384 + j];
    hr += bh[j]; hz += bh[192 + j]; hn += bh[384 + j];
    float r  = 1.f / (1.f + __expf(-(gr + hr)));
    float z  = 1.f / (1.f + __expf(-(gz + hz)));
    float nn = tanhf(gn + r * hn);
    float mn = (1.f - z) * nn + z * hv;

    float s1 = mn, s2 = mn * mn;
    #pragma unroll
    for (int o = 32; o > 0; o >>= 1) { s1 += __shfl_xor(s1, o); s2 += __shfl_xor(s2, o); }
    int wave = j >> 6, lane = j & 63;
    if (lane == 0) { red[wave] = s1; red[4 + wave] = s2; }
    __syncthreads();
    float ts = red[0] + red[1] + red[2], ts2 = red[4] + red[5] + red[6];
    float mean = ts * (1.f / 192.f);
    float var  = ts2 * (1.f / 192.f) - mean * mean;
    float rstd = rsqrtf(var + 1e-5f);
    lnm[j] = (mn - mean) * rstd * lng[j] + lnb[j];
    __syncthreads();

    {
        float acc = 0.f;
        for (int k = 0; k < 192; ++k) acc += lnm[k] * W1[k * 256 + j];
        h1[j] = fmaxf(acc + b1[j], 0.f);
        if (j < 64) {
            float acc2 = 0.f;
            for (int k = 0; k < 192; ++k) acc2 += lnm[k] * W1[k * 256 + 192 + j];
            h1[192 + j] = fmaxf(acc2 + b1[192 + j], 0.f);
        }
    }
    __syncthreads();
    float resj = b2[j];
    for (int c = 0; c < 256; ++c) resj += h1[c] * W2[c * 192 + j];
    fnew[row * 192 + j] = mn + resj;
}

// ---------------------------------------------------------------- per-iter: slot means (round-1 verbatim)
__global__ __launch_bounds__(256) void k_means(
    const float* __restrict__ fnew, float* __restrict__ oview, float* __restrict__ oattr)
{
    int t = blockIdx.x * 256 + threadIdx.x;
    if (t < 2048) {
        int bv = t >> 6, d = t & 63;
        float a = 0.f;
        #pragma unroll
        for (int s = 0; s < 7; ++s) a += fnew[(bv * 7 + s) * 192 + d];
        oview[t] = a * (1.f / 7.f);
    } else if (t < 9216) {
        int u = t - 2048;
        int b = u / 896, r = u % 896, s = r >> 7, d = r & 127;
        float a = 0.f;
        #pragma unroll
        for (int v = 0; v < 4; ++v) a += fnew[((b * 4 + v) * 7 + s) * 192 + 64 + d];
        oattr[u] = a * 0.25f;
    }
}

// ---------------------------------------------------------------- host
extern "C" void kernel_launch(void* const* d_in, const int* in_sizes, int n_in,
                              void* d_out, int out_size, void* d_ws, size_t ws_size,
                              hipStream_t stream)
{
    const float* x          = (const float*)d_in[0];
    const float* noise_view = (const float*)d_in[1];
    const float* noise_obj  = (const float*)d_in[2];
    const float* noise_bck  = (const float*)d_in[3];
    const float* ln_in_g    = (const float*)d_in[4];
    const float* ln_in_b    = (const float*)d_in[5];
    const float* ln_qry_g   = (const float*)d_in[6];
    const float* ln_qry_b   = (const float*)d_in[7];
    const float* ln_res_g   = (const float*)d_in[8];
    const float* ln_res_b   = (const float*)d_in[9];
    const float* view_loc   = (const float*)d_in[10];
    const float* view_lscl  = (const float*)d_in[11];
    const float* ao_loc     = (const float*)d_in[12];
    const float* ao_scl     = (const float*)d_in[13];
    const float* ab_loc     = (const float*)d_in[14];
    const float* ab_scl     = (const float*)d_in[15];
    const float* W_qry      = (const float*)d_in[16];
    const float* W_key      = (const float*)d_in[17];
    const float* W_val      = (const float*)d_in[18];
    const float* gru_Wi     = (const float*)d_in[19];
    const float* gru_Wh     = (const float*)d_in[20];
    const float* gru_bi     = (const float*)d_in[21];
    const float* gru_bh     = (const float*)d_in[22];
    const float* mlp_W1     = (const float*)d_in[23];
    const float* mlp_b1     = (const float*)d_in[24];
    const float* mlp_W2     = (const float*)d_in[25];
    const float* mlp_b2     = (const float*)d_in[26];

    char* ws = (char*)d_ws;
    size_t off = 0;
    auto alloc = [&](size_t bytes) { void* p = ws + off; off += (bytes + 255) & ~255ULL; return p; };
    unsigned short* xkv = (unsigned short*)alloc(131072UL * 320 * 2);   // 80 MB
    unsigned short* Wt  = (unsigned short*)alloc(320UL * 256 * 2);
    unsigned short* qbf = (unsigned short*)alloc(32UL * 16 * 128 * 2);
    float* pU    = (float*)alloc(32UL * 16 * 7 * 192 * 4);              // 2.75 MB
    float* pZ    = (float*)alloc(32UL * 16 * 7 * 4);
    float* fullb = (float*)alloc(224UL * 192 * 4);
    float* fnew  = (float*)alloc(224UL * 192 * 4);
    float* sview = (float*)alloc(2048UL * 4);
    float* sattr = (float*)alloc(7168UL * 4);

    k_prep<<<dim3(360), dim3(256), 0, stream>>>(
        W_key, W_val, view_loc, view_lscl, noise_view,
        ao_loc, ao_scl, noise_obj, ab_loc, ab_scl, noise_bck,
        Wt, qbf, sview, sattr);
    k_lnkv<<<dim3(2048), dim3(256), 0, stream>>>(x, ln_in_g, ln_in_b, Wt, xkv);

    for (int it = 0; it < 3; ++it) {
        k_qry<<<dim3(224), dim3(192), 0, stream>>>(sview, sattr, ln_qry_g, ln_qry_b, W_qry, fullb, qbf);
        k_att<<<dim3(512), dim3(256), 0, stream>>>(qbf, xkv, pU, pZ);
        k_gru<<<dim3(224), dim3(192), 0, stream>>>(pU, pZ, fullb, gru_Wi, gru_Wh, gru_bi, gru_bh,
                                                   ln_res_g, ln_res_b, mlp_W1, mlp_b1, mlp_W2, mlp_b2, fnew);
        float* ov = (it == 2) ? (float*)d_out : sview;
        float* oa = (it == 2) ? ((float*)d_out) + 2048 : sattr;
        k_means<<<dim3(36), dim3(256), 0, stream>>>(fnew, ov, oa);
    }
}

// Round 6
// 329.767 us; speedup vs baseline: 1.1179x; 1.1179x over previous
//
#include <hip/hip_runtime.h>
#include <cstdint>
#include <cstddef>

// ---------------------------------------------------------------- types
typedef float  f32x4 __attribute__((ext_vector_type(4)));
typedef short  s16x8 __attribute__((ext_vector_type(8)));
typedef __bf16 bf16x8 __attribute__((ext_vector_type(8)));

static __device__ __forceinline__ f32x4 mfma16(s16x8 a, s16x8 b, f32x4 c) {
    return __builtin_amdgcn_mfma_f32_16x16x32_bf16(
        __builtin_bit_cast(bf16x8, a), __builtin_bit_cast(bf16x8, b), c, 0, 0, 0);
}

static __device__ __forceinline__ unsigned short f2bf(float f) {
    unsigned int u = __builtin_bit_cast(unsigned int, f);
    u = (u + 0x7fffu + ((u >> 16) & 1u)) >> 16;
    return (unsigned short)u;
}
static __device__ __forceinline__ float bf2f(unsigned short h) {
    unsigned int u = ((unsigned int)h) << 16;
    return __builtin_bit_cast(float, u);
}

#define COEF 0.08838834764831845f

// ---------------------------------------------------------------- prep (round-1 verbatim)
__global__ __launch_bounds__(256) void k_prep(
    const float* __restrict__ Wkey, const float* __restrict__ Wval,
    const float* __restrict__ vloc, const float* __restrict__ vlscl, const float* __restrict__ nview,
    const float* __restrict__ aoloc, const float* __restrict__ aoscl, const float* __restrict__ nobj,
    const float* __restrict__ abloc, const float* __restrict__ abscl, const float* __restrict__ nbck,
    unsigned short* __restrict__ Wt, unsigned short* __restrict__ qbf,
    float* __restrict__ sview, float* __restrict__ sattr)
{
    int blk = blockIdx.x, t = threadIdx.x;
    if (blk < 320) {
        float v = (blk < 128) ? Wkey[t * 128 + blk] : Wval[t * 192 + (blk - 128)];
        Wt[blk * 256 + t] = f2bf(v);
    } else if (blk < 356) {
        int g = (blk - 320) * 256 + t;
        if (g < 2048) {
            int d = g & 63;
            sview[g] = vloc[d] + __expf(vlscl[d]) * nview[g];
        } else {
            int u = g - 2048;               // [b][s][128]
            int b = u / 896, r = u % 896, s = r >> 7, d = r & 127;
            float val;
            if (s < 6) val = aoloc[d] + __expf(aoscl[d]) * nobj[(b * 6 + s) * 128 + d];
            else       val = abloc[d] + __expf(abscl[d]) * nbck[b * 128 + d];
            sattr[u] = val;
        }
    } else {
        for (int e = (blk - 356) * 256 + t; e < 32 * 9 * 128; e += 1024) {
            int bv = e / 1152, r = e % 1152, s = 7 + r / 128, k = r & 127;
            qbf[(bv * 16 + s) * 128 + k] = 0;
        }
    }
}

// ---------------------------------------------------------------- phase A, split 1/2:
// pure LN stream: x f32 -> xb bf16 [131072][256]. One row per wave, no LDS,
// no barriers, low VGPR -> high occupancy TLP hides the shuffle chains.
__global__ __launch_bounds__(256) void k_ln(
    const float* __restrict__ x, const float* __restrict__ lng, const float* __restrict__ lnb,
    unsigned short* __restrict__ xb)
{
    const int lane = threadIdx.x & 63;
    const long row = (long)blockIdx.x * 4 + (threadIdx.x >> 6);
    float4 xv = *(const float4*)(x + row * 256 + lane * 4);
    float s1 = xv.x + xv.y + xv.z + xv.w;
    float s2 = xv.x * xv.x + xv.y * xv.y + xv.z * xv.z + xv.w * xv.w;
    #pragma unroll
    for (int o = 32; o > 0; o >>= 1) { s1 += __shfl_xor(s1, o); s2 += __shfl_xor(s2, o); }
    float mean = s1 * (1.f / 256.f);
    float var  = s2 * (1.f / 256.f) - mean * mean;
    float rstd = rsqrtf(var + 1e-5f);
    float4 gv = *(const float4*)(lng + lane * 4);
    float4 bv = *(const float4*)(lnb + lane * 4);
    float y0 = (xv.x - mean) * rstd * gv.x + bv.x;
    float y1 = (xv.y - mean) * rstd * gv.y + bv.y;
    float y2 = (xv.z - mean) * rstd * gv.z + bv.z;
    float y3 = (xv.w - mean) * rstd * gv.w + bv.w;
    unsigned u0 = (unsigned)f2bf(y0) | ((unsigned)f2bf(y1) << 16);
    unsigned u1 = (unsigned)f2bf(y2) | ((unsigned)f2bf(y3) << 16);
    *(uint2*)(xb + row * 256 + lane * 4) = make_uint2(u0, u1);
}

// ---------------------------------------------------------------- phase A, split 2/2:
// GEMM: xb bf16 @ Wt -> xkv bf16 [131072][320]. Staging is a pure 8x16B copy
// (no reductions); MFMA body identical to the measured r1 kernel.
__global__ __launch_bounds__(256) void k_gemm(
    const unsigned short* __restrict__ xb, const unsigned short* __restrict__ Wt,
    unsigned short* __restrict__ xkv)
{
    __shared__ unsigned short lds[64 * 320];        // 40 KB
    const int t = threadIdx.x, wave = t >> 6, lane = t & 63;
    const int l15 = lane & 15, lg = lane >> 4;
    const long rowbase = (long)blockIdx.x * 64;

    // ---- stage 64 rows x 512B into swizzled LDS, 16B units, coalesced
    const uint4* srcA = (const uint4*)(xb + rowbase * 256);
    #pragma unroll
    for (int i = 0; i < 8; ++i) {
        int unit = i * 256 + t;                    // 0..2047
        int row = unit >> 5, u = unit & 31;
        uint4 v = srcA[unit];
        *(uint4*)((char*)lds + row * 512 + ((u * 16) ^ ((row & 7) << 4))) = v;
    }
    __syncthreads();

    // ---- GEMM: wave owns 80 output cols (5 n-tiles), all 64 rows (4 m-tiles)
    f32x4 acc[4][5];
    #pragma unroll
    for (int mt = 0; mt < 4; ++mt)
        #pragma unroll
        for (int nt = 0; nt < 5; ++nt) acc[mt][nt] = (f32x4){0.f, 0.f, 0.f, 0.f};

    const int nb = wave * 80;
    #pragma unroll
    for (int kk = 0; kk < 8; ++kk) {
        s16x8 a[4], b[5];
        #pragma unroll
        for (int mt = 0; mt < 4; ++mt) {
            int row = mt * 16 + l15;
            int off = row * 512 + ((kk * 64 + lg * 16) ^ ((row & 7) << 4));
            a[mt] = *(const s16x8*)((char*)lds + off);
        }
        #pragma unroll
        for (int nt = 0; nt < 5; ++nt) {
            int col = nb + nt * 16 + l15;
            b[nt] = *(const s16x8*)(Wt + col * 256 + kk * 32 + lg * 8);
        }
        #pragma unroll
        for (int mt = 0; mt < 4; ++mt)
            #pragma unroll
            for (int nt = 0; nt < 5; ++nt)
                acc[mt][nt] = mfma16(a[mt], b[nt], acc[mt][nt]);
    }
    __syncthreads();

    // ---- C -> LDS (bf16), then coalesced store
    #pragma unroll
    for (int mt = 0; mt < 4; ++mt)
        #pragma unroll
        for (int nt = 0; nt < 5; ++nt)
            #pragma unroll
            for (int rg = 0; rg < 4; ++rg) {
                int row = mt * 16 + lg * 4 + rg;
                int col = nb + nt * 16 + l15;
                lds[row * 320 + col] = f2bf(acc[mt][nt][rg]);
            }
    __syncthreads();
    const uint4* src = (const uint4*)lds;
    uint4* dst = (uint4*)(xkv + rowbase * 320);
    #pragma unroll
    for (int j = 0; j < 10; ++j) dst[j * 256 + t] = src[j * 256 + t];
}

// ---------------------------------------------------------------- phase A fallback (round-1 verbatim fused)
__global__ __launch_bounds__(256) void k_lnkv(
    const float* __restrict__ x, const float* __restrict__ lng, const float* __restrict__ lnb,
    const unsigned short* __restrict__ Wt, unsigned short* __restrict__ xkv)
{
    __shared__ unsigned short lds[64 * 320];        // 40 KB
    const int t = threadIdx.x, wave = t >> 6, lane = t & 63;
    const int l15 = lane & 15, lg = lane >> 4;
    const long rowbase = (long)blockIdx.x * 64;

    float4 gv = *(const float4*)(lng + lane * 4);
    float4 bv = *(const float4*)(lnb + lane * 4);
    for (int r = 0; r < 16; ++r) {
        int row = wave * 16 + r;
        float4 xv = *(const float4*)(x + (rowbase + row) * 256 + lane * 4);
        float s1 = xv.x + xv.y + xv.z + xv.w;
        float s2 = xv.x * xv.x + xv.y * xv.y + xv.z * xv.z + xv.w * xv.w;
        #pragma unroll
        for (int o = 32; o > 0; o >>= 1) { s1 += __shfl_xor(s1, o); s2 += __shfl_xor(s2, o); }
        float mean = s1 * (1.f / 256.f);
        float var  = s2 * (1.f / 256.f) - mean * mean;
        float rstd = rsqrtf(var + 1e-5f);
        float y0 = (xv.x - mean) * rstd * gv.x + bv.x;
        float y1 = (xv.y - mean) * rstd * gv.y + bv.y;
        float y2 = (xv.z - mean) * rstd * gv.z + bv.z;
        float y3 = (xv.w - mean) * rstd * gv.w + bv.w;
        unsigned int u0 = (unsigned)f2bf(y0) | ((unsigned)f2bf(y1) << 16);
        unsigned int u1 = (unsigned)f2bf(y2) | ((unsigned)f2bf(y3) << 16);
        int off = row * 512 + ((lane * 8) ^ ((row & 7) << 4));
        *(uint2*)((char*)lds + off) = make_uint2(u0, u1);
    }
    __syncthreads();

    f32x4 acc[4][5];
    #pragma unroll
    for (int mt = 0; mt < 4; ++mt)
        #pragma unroll
        for (int nt = 0; nt < 5; ++nt) acc[mt][nt] = (f32x4){0.f, 0.f, 0.f, 0.f};

    const int nb = wave * 80;
    #pragma unroll
    for (int kk = 0; kk < 8; ++kk) {
        s16x8 a[4], b[5];
        #pragma unroll
        for (int mt = 0; mt < 4; ++mt) {
            int row = mt * 16 + l15;
            int off = row * 512 + ((kk * 64 + lg * 16) ^ ((row & 7) << 4));
            a[mt] = *(const s16x8*)((char*)lds + off);
        }
        #pragma unroll
        for (int nt = 0; nt < 5; ++nt) {
            int col = nb + nt * 16 + l15;
            b[nt] = *(const s16x8*)(Wt + col * 256 + kk * 32 + lg * 8);
        }
        #pragma unroll
        for (int mt = 0; mt < 4; ++mt)
            #pragma unroll
            for (int nt = 0; nt < 5; ++nt)
                acc[mt][nt] = mfma16(a[mt], b[nt], acc[mt][nt]);
    }
    __syncthreads();

    #pragma unroll
    for (int mt = 0; mt < 4; ++mt)
        #pragma unroll
        for (int nt = 0; nt < 5; ++nt)
            #pragma unroll
            for (int rg = 0; rg < 4; ++rg) {
                int row = mt * 16 + lg * 4 + rg;
                int col = nb + nt * 16 + l15;
                lds[row * 320 + col] = f2bf(acc[mt][nt][rg]);
            }
    __syncthreads();
    const uint4* src = (const uint4*)lds;
    uint4* dst = (uint4*)(xkv + rowbase * 320);
    #pragma unroll
    for (int j = 0; j < 10; ++j) dst[j * 256 + t] = src[j * 256 + t];
}

// ---------------------------------------------------------------- per-iter: q (round-1 verbatim)
__global__ __launch_bounds__(192) void k_qry(
    const float* __restrict__ sview, const float* __restrict__ sattr,
    const float* __restrict__ lng, const float* __restrict__ lnb,
    const float* __restrict__ Wq, float* __restrict__ full, unsigned short* __restrict__ qbf)
{
    int row = blockIdx.x;                  // bv*7 + s
    int bv = row / 7, s = row % 7, b = bv >> 2;
    int j = threadIdx.x;
    __shared__ float fr[192];
    __shared__ float red[8];
    float v = (j < 64) ? sview[bv * 64 + j] : sattr[(b * 7 + s) * 128 + (j - 64)];
    full[row * 192 + j] = v;
    float s1 = v, s2 = v * v;
    #pragma unroll
    for (int o = 32; o > 0; o >>= 1) { s1 += __shfl_xor(s1, o); s2 += __shfl_xor(s2, o); }
    int wave = j >> 6, lane = j & 63;
    if (lane == 0) { red[wave] = s1; red[4 + wave] = s2; }
    __syncthreads();
    float ts = red[0] + red[1] + red[2], ts2 = red[4] + red[5] + red[6];
    float mean = ts * (1.f / 192.f);
    float var  = ts2 * (1.f / 192.f) - mean * mean;
    float rstd = rsqrtf(var + 1e-5f);
    fr[j] = (v - mean) * rstd * lng[j] + lnb[j];
    __syncthreads();
    if (j < 128) {
        float acc = 0.f;
        for (int k = 0; k < 192; ++k) acc += fr[k] * Wq[k * 128 + j];
        qbf[(bv * 16 + s) * 128 + j] = f2bf(acc * COEF);
    }
}

// ---------------------------------------------------------------- per-iter: attn weights (round-1 verbatim)
__global__ __launch_bounds__(256) void k_attn(
    const unsigned short* __restrict__ qbf, const unsigned short* __restrict__ xkv,
    float* __restrict__ wbuf)
{
    int blk = blockIdx.x;                  // 512 = 32 bv * 16 chunks(256 n)
    int bv = blk >> 4, chunk = blk & 15;
    int t = threadIdx.x, wave = t >> 6, lane = t & 63;
    int l15 = lane & 15, lg = lane >> 4;

    s16x8 aq[4];
    const unsigned short* qrow = qbf + (bv * 16 + l15) * 128 + lg * 8;
    #pragma unroll
    for (int kk = 0; kk < 4; ++kk) aq[kk] = *(const s16x8*)(qrow + kk * 32);

    for (int tt = 0; tt < 4; ++tt) {
        int ntb = chunk * 256 + (wave * 4 + tt) * 16;
        const unsigned short* xr = xkv + ((long)(bv * 4096 + ntb + l15)) * 320 + lg * 8;
        f32x4 acc = (f32x4){0.f, 0.f, 0.f, 0.f};
        #pragma unroll
        for (int kk = 0; kk < 4; ++kk) {
            s16x8 bfr = *(const s16x8*)(xr + kk * 32);
            acc = mfma16(aq[kk], bfr, acc);
        }
        float o0 = __shfl_xor(acc[0], 16), o1 = __shfl_xor(acc[1], 16);
        float o2 = __shfl_xor(acc[2], 16), o3 = __shfl_xor(acc[3], 16);
        bool hi = (lg & 1);
        float v0 = hi ? o0 : acc[0], v1 = hi ? o1 : acc[1];
        float v2 = hi ? o2 : acc[2], v3 = hi ? o3 : acc[3];
        float v4 = hi ? acc[0] : o0, v5 = hi ? acc[1] : o1, v6 = hi ? acc[2] : o2;
        float m = fmaxf(fmaxf(fmaxf(v0, v1), fmaxf(v2, v3)), fmaxf(fmaxf(v4, v5), v6));
        float e0 = __expf(v0 - m), e1 = __expf(v1 - m), e2 = __expf(v2 - m), e3 = __expf(v3 - m);
        float e4 = __expf(v4 - m), e5 = __expf(v5 - m), e6 = __expf(v6 - m);
        float inv = 1.f / (e0 + e1 + e2 + e3 + e4 + e5 + e6);
        if (lg < 2) {
            int n = ntb + l15;
            float4 out = (lg == 0) ? make_float4(e0 * inv, e1 * inv, e2 * inv, e3 * inv)
                                   : make_float4(e4 * inv, e5 * inv, e6 * inv, 0.f);
            *(float4*)(wbuf + ((long)(bv * 4096 + n)) * 8 + lg * 4) = out;
        }
    }
}

// ---------------------------------------------------------------- per-iter: updates partials (round-1 verbatim)
__global__ __launch_bounds__(192) void k_upd(
    const float* __restrict__ wbuf, const unsigned short* __restrict__ xkv,
    float* __restrict__ pU, float* __restrict__ pZ)
{
    int blk = blockIdx.x;                  // 512 = 32 bv * 16 chunks(256 n)
    int bv = blk >> 4, chunk = blk & 15;
    int n0 = chunk * 256;
    int t = threadIdx.x;
    __shared__ float wl[256 * 8];
    for (int idx = t; idx < 2048; idx += 192)
        wl[idx] = wbuf[((long)(bv * 4096 + n0)) * 8 + idx];
    __syncthreads();
    float a0 = 0, a1 = 0, a2 = 0, a3 = 0, a4 = 0, a5 = 0, a6 = 0;
    const unsigned short* xp = xkv + ((long)(bv * 4096 + n0)) * 320 + 128 + t;
    for (int n = 0; n < 256; ++n) {
        float xv = bf2f(xp[n * 320]);
        float4 wa = *(const float4*)(wl + n * 8);
        float4 wb = *(const float4*)(wl + n * 8 + 4);
        a0 += wa.x * xv; a1 += wa.y * xv; a2 += wa.z * xv; a3 += wa.w * xv;
        a4 += wb.x * xv; a5 += wb.y * xv; a6 += wb.z * xv;
    }
    long base = (((long)bv * 16 + chunk) * 7) * 192 + t;
    pU[base + 0 * 192] = a0; pU[base + 1 * 192] = a1; pU[base + 2 * 192] = a2;
    pU[base + 3 * 192] = a3; pU[base + 4 * 192] = a4; pU[base + 5 * 192] = a5;
    pU[base + 6 * 192] = a6;
    if (t < 7) {
        float z = 0.f;
        for (int n = 0; n < 256; ++n) z += wl[n * 8 + t];
        pZ[(bv * 16 + chunk) * 7 + t] = z;
    }
}

// ---------------------------------------------------------------- per-iter: GRU+MLP (round-1 verbatim, f32 weights)
__global__ __launch_bounds__(192) void k_gru(
    const float* __restrict__ pU, const float* __restrict__ pZ, const float* __restrict__ full,
    const float* __restrict__ Wi, const float* __restrict__ Wh,
    const float* __restrict__ bi, const float* __restrict__ bh,
    const float* __restrict__ lng, const float* __restrict__ lnb,
    const float* __restrict__ W1, const float* __restrict__ b1,
    const float* __restrict__ W2, const float* __restrict__ b2,
    float* __restrict__ fnew)
{
    int row = blockIdx.x;                  // bv*7 + s
    int bv = row / 7, s = row % 7;
    int j = threadIdx.x;
    __shared__ float u[192], h[192], lnm[192], h1[256], red[8];

    float us = 0.f;
    #pragma unroll
    for (int c = 0; c < 16; ++c) us += pU[(((long)bv * 16 + c) * 7 + s) * 192 + j];
    float Z = 0.f;
    #pragma unroll
    for (int c = 0; c < 16; ++c) Z += pZ[(bv * 16 + c) * 7 + s];
    us /= Z;
    u[j] = us;
    float hv = full[row * 192 + j];
    h[j] = hv;
    __syncthreads();

    float gr = 0, gz = 0, gn = 0, hr = 0, hz = 0, hn = 0;
    for (int k = 0; k < 192; ++k) {
        float uk = u[k], hk = h[k];
        const float* wik = Wi + k * 576 + j;
        const float* whk = Wh + k * 576 + j;
        gr += uk * wik[0];   gz += uk * wik[192]; gn += uk * wik[384];
        hr += hk * whk[0];   hz += hk * whk[192]; hn += hk * whk[384];
    }
    gr += bi[j]; gz += bi[192 + j]; gn += bi[384 + j];
    hr += bh[j]; hz += bh[192 + j]; hn += bh[384 + j];
    float r  = 1.f / (1.f + __expf(-(gr + hr)));
    float z  = 1.f / (1.f + __expf(-(gz + hz)));
    float nn = tanhf(gn + r * hn);
    float mn = (1.f - z) * nn + z * hv;

    float s1 = mn, s2 = mn * mn;
    #pragma unroll
    for (int o = 32; o > 0; o >>= 1) { s1 += __shfl_xor(s1, o); s2 += __shfl_xor(s2, o); }
    int wave = j >> 6, lane = j & 63;
    if (lane == 0) { red[wave] = s1; red[4 + wave] = s2; }
    __syncthreads();
    float ts = red[0] + red[1] + red[2], ts2 = red[4] + red[5] + red[6];
    float mean = ts * (1.f / 192.f);
    float var  = ts2 * (1.f / 192.f) - mean * mean;
    float rstd = rsqrtf(var + 1e-5f);
    lnm[j] = (mn - mean) * rstd * lng[j] + lnb[j];
    __syncthreads();

    {
        float acc = 0.f;
        for (int k = 0; k < 192; ++k) acc += lnm[k] * W1[k * 256 + j];
        h1[j] = fmaxf(acc + b1[j], 0.f);
        if (j < 64) {
            float acc2 = 0.f;
            for (int k = 0; k < 192; ++k) acc2 += lnm[k] * W1[k * 256 + 192 + j];
            h1[192 + j] = fmaxf(acc2 + b1[192 + j], 0.f);
        }
    }
    __syncthreads();
    float resj = b2[j];
    for (int c = 0; c < 256; ++c) resj += h1[c] * W2[c * 192 + j];
    fnew[row * 192 + j] = mn + resj;
}

// ---------------------------------------------------------------- per-iter: slot means (round-1 verbatim)
__global__ __launch_bounds__(256) void k_means(
    const float* __restrict__ fnew, float* __restrict__ oview, float* __restrict__ oattr)
{
    int t = blockIdx.x * 256 + threadIdx.x;
    if (t < 2048) {
        int bv = t >> 6, d = t & 63;
        float a = 0.f;
        #pragma unroll
        for (int s = 0; s < 7; ++s) a += fnew[(bv * 7 + s) * 192 + d];
        oview[t] = a * (1.f / 7.f);
    } else if (t < 9216) {
        int u = t - 2048;
        int b = u / 896, r = u % 896, s = r >> 7, d = r & 127;
        float a = 0.f;
        #pragma unroll
        for (int v = 0; v < 4; ++v) a += fnew[((b * 4 + v) * 7 + s) * 192 + 64 + d];
        oattr[u] = a * 0.25f;
    }
}

// ---------------------------------------------------------------- host
extern "C" void kernel_launch(void* const* d_in, const int* in_sizes, int n_in,
                              void* d_out, int out_size, void* d_ws, size_t ws_size,
                              hipStream_t stream)
{
    const float* x          = (const float*)d_in[0];
    const float* noise_view = (const float*)d_in[1];
    const float* noise_obj  = (const float*)d_in[2];
    const float* noise_bck  = (const float*)d_in[3];
    const float* ln_in_g    = (const float*)d_in[4];
    const float* ln_in_b    = (const float*)d_in[5];
    const float* ln_qry_g   = (const float*)d_in[6];
    const float* ln_qry_b   = (const float*)d_in[7];
    const float* ln_res_g   = (const float*)d_in[8];
    const float* ln_res_b   = (const float*)d_in[9];
    const float* view_loc   = (const float*)d_in[10];
    const float* view_lscl  = (const float*)d_in[11];
    const float* ao_loc     = (const float*)d_in[12];
    const float* ao_scl     = (const float*)d_in[13];
    const float* ab_loc     = (const float*)d_in[14];
    const float* ab_scl     = (const float*)d_in[15];
    const float* W_qry      = (const float*)d_in[16];
    const float* W_key      = (const float*)d_in[17];
    const float* W_val      = (const float*)d_in[18];
    const float* gru_Wi     = (const float*)d_in[19];
    const float* gru_Wh     = (const float*)d_in[20];
    const float* gru_bi     = (const float*)d_in[21];
    const float* gru_bh     = (const float*)d_in[22];
    const float* mlp_W1     = (const float*)d_in[23];
    const float* mlp_b1     = (const float*)d_in[24];
    const float* mlp_W2     = (const float*)d_in[25];
    const float* mlp_b2     = (const float*)d_in[26];

    char* ws = (char*)d_ws;
    size_t off = 0;
    auto alloc = [&](size_t bytes) { void* p = ws + off; off += (bytes + 255) & ~255ULL; return p; };
    unsigned short* xkv = (unsigned short*)alloc(131072UL * 320 * 2);   // 80 MB
    unsigned short* Wt  = (unsigned short*)alloc(320UL * 256 * 2);
    unsigned short* qbf = (unsigned short*)alloc(32UL * 16 * 128 * 2);
    float* wbuf  = (float*)alloc(32UL * 4096 * 8 * 4);                  // 4 MB
    float* pU    = (float*)alloc(32UL * 16 * 7 * 192 * 4);              // 2.75 MB
    float* pZ    = (float*)alloc(32UL * 16 * 7 * 4);
    float* fullb = (float*)alloc(224UL * 192 * 4);
    float* fnew  = (float*)alloc(224UL * 192 * 4);
    float* sview = (float*)alloc(2048UL * 4);
    float* sattr = (float*)alloc(7168UL * 4);
    unsigned short* xb = (unsigned short*)alloc(131072UL * 256 * 2);    // 64 MB (split path)
    bool use_split = (off <= ws_size);

    k_prep<<<dim3(360), dim3(256), 0, stream>>>(
        W_key, W_val, view_loc, view_lscl, noise_view,
        ao_loc, ao_scl, noise_obj, ab_loc, ab_scl, noise_bck,
        Wt, qbf, sview, sattr);
    if (use_split) {
        k_ln  <<<dim3(32768), dim3(256), 0, stream>>>(x, ln_in_g, ln_in_b, xb);
        k_gemm<<<dim3(2048),  dim3(256), 0, stream>>>(xb, Wt, xkv);
    } else {
        k_lnkv<<<dim3(2048), dim3(256), 0, stream>>>(x, ln_in_g, ln_in_b, Wt, xkv);
    }

    for (int it = 0; it < 3; ++it) {
        k_qry<<<dim3(224), dim3(192), 0, stream>>>(sview, sattr, ln_qry_g, ln_qry_b, W_qry, fullb, qbf);
        k_attn<<<dim3(512), dim3(256), 0, stream>>>(qbf, xkv, wbuf);
        k_upd<<<dim3(512), dim3(192), 0, stream>>>(wbuf, xkv, pU, pZ);
        k_gru<<<dim3(224), dim3(192), 0, stream>>>(pU, pZ, fullb, gru_Wi, gru_Wh, gru_bi, gru_bh,
                                                   ln_res_g, ln_res_b, mlp_W1, mlp_b1, mlp_W2, mlp_b2, fnew);
        float* ov = (it == 2) ? (float*)d_out : sview;
        float* oa = (it == 2) ? ((float*)d_out) + 2048 : sattr;
        k_means<<<dim3(36), dim3(256), 0, stream>>>(fnew, ov, oa);
    }
}

// Round 7
// 281.204 us; speedup vs baseline: 1.3110x; 1.1727x over previous
//
#include <hip/hip_runtime.h>
#include <cstdint>
#include <cstddef>

// ---------------------------------------------------------------- types
typedef float  f32x4 __attribute__((ext_vector_type(4)));
typedef short  s16x8 __attribute__((ext_vector_type(8)));
typedef __bf16 bf16x8 __attribute__((ext_vector_type(8)));

static __device__ __forceinline__ f32x4 mfma16(s16x8 a, s16x8 b, f32x4 c) {
    return __builtin_amdgcn_mfma_f32_16x16x32_bf16(
        __builtin_bit_cast(bf16x8, a), __builtin_bit_cast(bf16x8, b), c, 0, 0, 0);
}

static __device__ __forceinline__ unsigned short f2bf(float f) {
    unsigned int u = __builtin_bit_cast(unsigned int, f);
    u = (u + 0x7fffu + ((u >> 16) & 1u)) >> 16;
    return (unsigned short)u;
}
static __device__ __forceinline__ float bf2f(unsigned short h) {
    unsigned int u = ((unsigned int)h) << 16;
    return __builtin_bit_cast(float, u);
}

#define COEF 0.08838834764831845f

// ---------------------------------------------------------------- prep (round-1 verbatim)
__global__ __launch_bounds__(256) void k_prep(
    const float* __restrict__ Wkey, const float* __restrict__ Wval,
    const float* __restrict__ vloc, const float* __restrict__ vlscl, const float* __restrict__ nview,
    const float* __restrict__ aoloc, const float* __restrict__ aoscl, const float* __restrict__ nobj,
    const float* __restrict__ abloc, const float* __restrict__ abscl, const float* __restrict__ nbck,
    unsigned short* __restrict__ Wt, unsigned short* __restrict__ qbf,
    float* __restrict__ sview, float* __restrict__ sattr)
{
    int blk = blockIdx.x, t = threadIdx.x;
    if (blk < 320) {
        float v = (blk < 128) ? Wkey[t * 128 + blk] : Wval[t * 192 + (blk - 128)];
        Wt[blk * 256 + t] = f2bf(v);
    } else if (blk < 356) {
        int g = (blk - 320) * 256 + t;
        if (g < 2048) {
            int d = g & 63;
            sview[g] = vloc[d] + __expf(vlscl[d]) * nview[g];
        } else {
            int u = g - 2048;               // [b][s][128]
            int b = u / 896, r = u % 896, s = r >> 7, d = r & 127;
            float val;
            if (s < 6) val = aoloc[d] + __expf(aoscl[d]) * nobj[(b * 6 + s) * 128 + d];
            else       val = abloc[d] + __expf(abscl[d]) * nbck[b * 128 + d];
            sattr[u] = val;
        }
    } else {
        for (int e = (blk - 356) * 256 + t; e < 32 * 9 * 128; e += 1024) {
            int bv = e / 1152, r = e % 1152, s = 7 + r / 128, k = r & 127;
            qbf[(bv * 16 + s) * 128 + k] = 0;
        }
    }
}

// ---------------------------------------------------------------- phase A (round-1 verbatim, measured 110.8 us)
__global__ __launch_bounds__(256) void k_lnkv(
    const float* __restrict__ x, const float* __restrict__ lng, const float* __restrict__ lnb,
    const unsigned short* __restrict__ Wt, unsigned short* __restrict__ xkv)
{
    __shared__ unsigned short lds[64 * 320];        // 40 KB
    const int t = threadIdx.x, wave = t >> 6, lane = t & 63;
    const int l15 = lane & 15, lg = lane >> 4;
    const long rowbase = (long)blockIdx.x * 64;

    float4 gv = *(const float4*)(lng + lane * 4);
    float4 bv = *(const float4*)(lnb + lane * 4);
    for (int r = 0; r < 16; ++r) {
        int row = wave * 16 + r;
        float4 xv = *(const float4*)(x + (rowbase + row) * 256 + lane * 4);
        float s1 = xv.x + xv.y + xv.z + xv.w;
        float s2 = xv.x * xv.x + xv.y * xv.y + xv.z * xv.z + xv.w * xv.w;
        #pragma unroll
        for (int o = 32; o > 0; o >>= 1) { s1 += __shfl_xor(s1, o); s2 += __shfl_xor(s2, o); }
        float mean = s1 * (1.f / 256.f);
        float var  = s2 * (1.f / 256.f) - mean * mean;
        float rstd = rsqrtf(var + 1e-5f);
        float y0 = (xv.x - mean) * rstd * gv.x + bv.x;
        float y1 = (xv.y - mean) * rstd * gv.y + bv.y;
        float y2 = (xv.z - mean) * rstd * gv.z + bv.z;
        float y3 = (xv.w - mean) * rstd * gv.w + bv.w;
        unsigned int u0 = (unsigned)f2bf(y0) | ((unsigned)f2bf(y1) << 16);
        unsigned int u1 = (unsigned)f2bf(y2) | ((unsigned)f2bf(y3) << 16);
        int off = row * 512 + ((lane * 8) ^ ((row & 7) << 4));
        *(uint2*)((char*)lds + off) = make_uint2(u0, u1);
    }
    __syncthreads();

    f32x4 acc[4][5];
    #pragma unroll
    for (int mt = 0; mt < 4; ++mt)
        #pragma unroll
        for (int nt = 0; nt < 5; ++nt) acc[mt][nt] = (f32x4){0.f, 0.f, 0.f, 0.f};

    const int nb = wave * 80;
    #pragma unroll
    for (int kk = 0; kk < 8; ++kk) {
        s16x8 a[4], b[5];
        #pragma unroll
        for (int mt = 0; mt < 4; ++mt) {
            int row = mt * 16 + l15;
            int off = row * 512 + ((kk * 64 + lg * 16) ^ ((row & 7) << 4));
            a[mt] = *(const s16x8*)((char*)lds + off);
        }
        #pragma unroll
        for (int nt = 0; nt < 5; ++nt) {
            int col = nb + nt * 16 + l15;
            b[nt] = *(const s16x8*)(Wt + col * 256 + kk * 32 + lg * 8);
        }
        #pragma unroll
        for (int mt = 0; mt < 4; ++mt)
            #pragma unroll
            for (int nt = 0; nt < 5; ++nt)
                acc[mt][nt] = mfma16(a[mt], b[nt], acc[mt][nt]);
    }
    __syncthreads();

    #pragma unroll
    for (int mt = 0; mt < 4; ++mt)
        #pragma unroll
        for (int nt = 0; nt < 5; ++nt)
            #pragma unroll
            for (int rg = 0; rg < 4; ++rg) {
                int row = mt * 16 + lg * 4 + rg;
                int col = nb + nt * 16 + l15;
                lds[row * 320 + col] = f2bf(acc[mt][nt][rg]);
            }
    __syncthreads();
    const uint4* src = (const uint4*)lds;
    uint4* dst = (uint4*)(xkv + rowbase * 320);
    #pragma unroll
    for (int j = 0; j < 10; ++j) dst[j * 256 + t] = src[j * 256 + t];
}

// ---------------------------------------------------------------- per-iter: q (round-1 verbatim)
__global__ __launch_bounds__(192) void k_qry(
    const float* __restrict__ sview, const float* __restrict__ sattr,
    const float* __restrict__ lng, const float* __restrict__ lnb,
    const float* __restrict__ Wq, float* __restrict__ full, unsigned short* __restrict__ qbf)
{
    int row = blockIdx.x;                  // bv*7 + s
    int bv = row / 7, s = row % 7, b = bv >> 2;
    int j = threadIdx.x;
    __shared__ float fr[192];
    __shared__ float red[8];
    float v = (j < 64) ? sview[bv * 64 + j] : sattr[(b * 7 + s) * 128 + (j - 64)];
    full[row * 192 + j] = v;
    float s1 = v, s2 = v * v;
    #pragma unroll
    for (int o = 32; o > 0; o >>= 1) { s1 += __shfl_xor(s1, o); s2 += __shfl_xor(s2, o); }
    int wave = j >> 6, lane = j & 63;
    if (lane == 0) { red[wave] = s1; red[4 + wave] = s2; }
    __syncthreads();
    float ts = red[0] + red[1] + red[2], ts2 = red[4] + red[5] + red[6];
    float mean = ts * (1.f / 192.f);
    float var  = ts2 * (1.f / 192.f) - mean * mean;
    float rstd = rsqrtf(var + 1e-5f);
    fr[j] = (v - mean) * rstd * lng[j] + lnb[j];
    __syncthreads();
    if (j < 128) {
        float acc = 0.f;
        for (int k = 0; k < 192; ++k) acc += fr[k] * Wq[k * 128 + j];
        qbf[(bv * 16 + s) * 128 + j] = f2bf(acc * COEF);
    }
}

// ---------------------------------------------------------------- per-iter: attn weights (round-1 verbatim)
__global__ __launch_bounds__(256) void k_attn(
    const unsigned short* __restrict__ qbf, const unsigned short* __restrict__ xkv,
    float* __restrict__ wbuf)
{
    int blk = blockIdx.x;                  // 512 = 32 bv * 16 chunks(256 n)
    int bv = blk >> 4, chunk = blk & 15;
    int t = threadIdx.x, wave = t >> 6, lane = t & 63;
    int l15 = lane & 15, lg = lane >> 4;

    s16x8 aq[4];
    const unsigned short* qrow = qbf + (bv * 16 + l15) * 128 + lg * 8;
    #pragma unroll
    for (int kk = 0; kk < 4; ++kk) aq[kk] = *(const s16x8*)(qrow + kk * 32);

    for (int tt = 0; tt < 4; ++tt) {
        int ntb = chunk * 256 + (wave * 4 + tt) * 16;
        const unsigned short* xr = xkv + ((long)(bv * 4096 + ntb + l15)) * 320 + lg * 8;
        f32x4 acc = (f32x4){0.f, 0.f, 0.f, 0.f};
        #pragma unroll
        for (int kk = 0; kk < 4; ++kk) {
            s16x8 bfr = *(const s16x8*)(xr + kk * 32);
            acc = mfma16(aq[kk], bfr, acc);
        }
        float o0 = __shfl_xor(acc[0], 16), o1 = __shfl_xor(acc[1], 16);
        float o2 = __shfl_xor(acc[2], 16), o3 = __shfl_xor(acc[3], 16);
        bool hi = (lg & 1);
        float v0 = hi ? o0 : acc[0], v1 = hi ? o1 : acc[1];
        float v2 = hi ? o2 : acc[2], v3 = hi ? o3 : acc[3];
        float v4 = hi ? acc[0] : o0, v5 = hi ? acc[1] : o1, v6 = hi ? acc[2] : o2;
        float m = fmaxf(fmaxf(fmaxf(v0, v1), fmaxf(v2, v3)), fmaxf(fmaxf(v4, v5), v6));
        float e0 = __expf(v0 - m), e1 = __expf(v1 - m), e2 = __expf(v2 - m), e3 = __expf(v3 - m);
        float e4 = __expf(v4 - m), e5 = __expf(v5 - m), e6 = __expf(v6 - m);
        float inv = 1.f / (e0 + e1 + e2 + e3 + e4 + e5 + e6);
        if (lg < 2) {
            int n = ntb + l15;
            float4 out = (lg == 0) ? make_float4(e0 * inv, e1 * inv, e2 * inv, e3 * inv)
                                   : make_float4(e4 * inv, e5 * inv, e6 * inv, 0.f);
            *(float4*)(wbuf + ((long)(bv * 4096 + n)) * 8 + lg * 4) = out;
        }
    }
}

// ---------------------------------------------------------------- per-iter: updates partials (round-1 verbatim)
__global__ __launch_bounds__(192) void k_upd(
    const float* __restrict__ wbuf, const unsigned short* __restrict__ xkv,
    float* __restrict__ pU, float* __restrict__ pZ)
{
    int blk = blockIdx.x;                  // 512 = 32 bv * 16 chunks(256 n)
    int bv = blk >> 4, chunk = blk & 15;
    int n0 = chunk * 256;
    int t = threadIdx.x;
    __shared__ float wl[256 * 8];
    for (int idx = t; idx < 2048; idx += 192)
        wl[idx] = wbuf[((long)(bv * 4096 + n0)) * 8 + idx];
    __syncthreads();
    float a0 = 0, a1 = 0, a2 = 0, a3 = 0, a4 = 0, a5 = 0, a6 = 0;
    const unsigned short* xp = xkv + ((long)(bv * 4096 + n0)) * 320 + 128 + t;
    for (int n = 0; n < 256; ++n) {
        float xv = bf2f(xp[n * 320]);
        float4 wa = *(const float4*)(wl + n * 8);
        float4 wb = *(const float4*)(wl + n * 8 + 4);
        a0 += wa.x * xv; a1 += wa.y * xv; a2 += wa.z * xv; a3 += wa.w * xv;
        a4 += wb.x * xv; a5 += wb.y * xv; a6 += wb.z * xv;
    }
    long base = (((long)bv * 16 + chunk) * 7) * 192 + t;
    pU[base + 0 * 192] = a0; pU[base + 1 * 192] = a1; pU[base + 2 * 192] = a2;
    pU[base + 3 * 192] = a3; pU[base + 4 * 192] = a4; pU[base + 5 * 192] = a5;
    pU[base + 6 * 192] = a6;
    if (t < 7) {
        float z = 0.f;
        for (int n = 0; n < 256; ++n) z += wl[n * 8 + t];
        pZ[(bv * 16 + chunk) * 7 + t] = z;
    }
}

// ---------------------------------------------------------------- per-iter: GRU+MLP v2 — gate-parallel, 576 threads
// Thread j in [0,576) owns one gate column; f32, summation order identical to r1.
__global__ __launch_bounds__(576) void k_gru(
    const float* __restrict__ pU, const float* __restrict__ pZ, const float* __restrict__ full,
    const float* __restrict__ Wi, const float* __restrict__ Wh,
    const float* __restrict__ bi, const float* __restrict__ bh,
    const float* __restrict__ lng, const float* __restrict__ lnb,
    const float* __restrict__ W1, const float* __restrict__ b1,
    const float* __restrict__ W2, const float* __restrict__ b2,
    float* __restrict__ fnew)
{
    int row = blockIdx.x;                  // bv*7 + s
    int bv = row / 7, s = row % 7;
    int j = threadIdx.x;
    __shared__ float u[192], h[192], gi[576], gh[576], lnm[192], h1[256], red[8];

    // ---- phase 1: u (pU/Z reduce) and h
    if (j < 192) {
        float us = 0.f;
        #pragma unroll
        for (int c = 0; c < 16; ++c) us += pU[(((long)bv * 16 + c) * 7 + s) * 192 + j];
        float Z = 0.f;
        #pragma unroll
        for (int c = 0; c < 16; ++c) Z += pZ[(bv * 16 + c) * 7 + s];
        u[j] = us / Z;
    } else if (j < 384) {
        int jj = j - 192;
        h[jj] = full[row * 192 + jj];
    }
    __syncthreads();

    // ---- phase 2: one gate column per thread (384 serial MACs, LDS broadcast reads)
    {
        float a = 0.f, b = 0.f;
        for (int k = 0; k < 192; ++k) {
            a += u[k] * Wi[k * 576 + j];
            b += h[k] * Wh[k * 576 + j];
        }
        gi[j] = a + bi[j];
        gh[j] = b + bh[j];
    }
    __syncthreads();

    // ---- phase 3: gates + GRU combine + LN (threads 0..191)
    float mn = 0.f;
    if (j < 192) {
        float hv = h[j];
        float r  = 1.f / (1.f + __expf(-(gi[j] + gh[j])));
        float z  = 1.f / (1.f + __expf(-(gi[192 + j] + gh[192 + j])));
        float nn = tanhf(gi[384 + j] + r * gh[384 + j]);
        mn = (1.f - z) * nn + z * hv;

        float s1 = mn, s2 = mn * mn;
        #pragma unroll
        for (int o = 32; o > 0; o >>= 1) { s1 += __shfl_xor(s1, o); s2 += __shfl_xor(s2, o); }
        int wave = j >> 6, lane = j & 63;
        if (lane == 0) { red[wave] = s1; red[4 + wave] = s2; }
    }
    __syncthreads();
    if (j < 192) {
        float ts = red[0] + red[1] + red[2], ts2 = red[4] + red[5] + red[6];
        float mean = ts * (1.f / 192.f);
        float var  = ts2 * (1.f / 192.f) - mean * mean;
        float rstd = rsqrtf(var + 1e-5f);
        lnm[j] = (mn - mean) * rstd * lng[j] + lnb[j];
    }
    __syncthreads();

    // ---- phase 4: MLP hidden (threads 0..255)
    if (j < 256) {
        float acc = 0.f;
        for (int k = 0; k < 192; ++k) acc += lnm[k] * W1[k * 256 + j];
        h1[j] = fmaxf(acc + b1[j], 0.f);
    }
    __syncthreads();

    // ---- phase 5: MLP out + residual (threads 0..191)
    if (j < 192) {
        float resj = b2[j];
        for (int c = 0; c < 256; ++c) resj += h1[c] * W2[c * 192 + j];
        fnew[row * 192 + j] = mn + resj;
    }
}

// ---------------------------------------------------------------- per-iter: slot means (round-1 verbatim)
__global__ __launch_bounds__(256) void k_means(
    const float* __restrict__ fnew, float* __restrict__ oview, float* __restrict__ oattr)
{
    int t = blockIdx.x * 256 + threadIdx.x;
    if (t < 2048) {
        int bv = t >> 6, d = t & 63;
        float a = 0.f;
        #pragma unroll
        for (int s = 0; s < 7; ++s) a += fnew[(bv * 7 + s) * 192 + d];
        oview[t] = a * (1.f / 7.f);
    } else if (t < 9216) {
        int u = t - 2048;
        int b = u / 896, r = u % 896, s = r >> 7, d = r & 127;
        float a = 0.f;
        #pragma unroll
        for (int v = 0; v < 4; ++v) a += fnew[((b * 4 + v) * 7 + s) * 192 + 64 + d];
        oattr[u] = a * 0.25f;
    }
}

// ---------------------------------------------------------------- host
extern "C" void kernel_launch(void* const* d_in, const int* in_sizes, int n_in,
                              void* d_out, int out_size, void* d_ws, size_t ws_size,
                              hipStream_t stream)
{
    const float* x          = (const float*)d_in[0];
    const float* noise_view = (const float*)d_in[1];
    const float* noise_obj  = (const float*)d_in[2];
    const float* noise_bck  = (const float*)d_in[3];
    const float* ln_in_g    = (const float*)d_in[4];
    const float* ln_in_b    = (const float*)d_in[5];
    const float* ln_qry_g   = (const float*)d_in[6];
    const float* ln_qry_b   = (const float*)d_in[7];
    const float* ln_res_g   = (const float*)d_in[8];
    const float* ln_res_b   = (const float*)d_in[9];
    const float* view_loc   = (const float*)d_in[10];
    const float* view_lscl  = (const float*)d_in[11];
    const float* ao_loc     = (const float*)d_in[12];
    const float* ao_scl     = (const float*)d_in[13];
    const float* ab_loc     = (const float*)d_in[14];
    const float* ab_scl     = (const float*)d_in[15];
    const float* W_qry      = (const float*)d_in[16];
    const float* W_key      = (const float*)d_in[17];
    const float* W_val      = (const float*)d_in[18];
    const float* gru_Wi     = (const float*)d_in[19];
    const float* gru_Wh     = (const float*)d_in[20];
    const float* gru_bi     = (const float*)d_in[21];
    const float* gru_bh     = (const float*)d_in[22];
    const float* mlp_W1     = (const float*)d_in[23];
    const float* mlp_b1     = (const float*)d_in[24];
    const float* mlp_W2     = (const float*)d_in[25];
    const float* mlp_b2     = (const float*)d_in[26];

    char* ws = (char*)d_ws;
    size_t off = 0;
    auto alloc = [&](size_t bytes) { void* p = ws + off; off += (bytes + 255) & ~255ULL; return p; };
    unsigned short* xkv = (unsigned short*)alloc(131072UL * 320 * 2);   // 80 MB
    unsigned short* Wt  = (unsigned short*)alloc(320UL * 256 * 2);
    unsigned short* qbf = (unsigned short*)alloc(32UL * 16 * 128 * 2);
    float* wbuf  = (float*)alloc(32UL * 4096 * 8 * 4);                  // 4 MB
    float* pU    = (float*)alloc(32UL * 16 * 7 * 192 * 4);              // 2.75 MB
    float* pZ    = (float*)alloc(32UL * 16 * 7 * 4);
    float* fullb = (float*)alloc(224UL * 192 * 4);
    float* fnew  = (float*)alloc(224UL * 192 * 4);
    float* sview = (float*)alloc(2048UL * 4);
    float* sattr = (float*)alloc(7168UL * 4);

    k_prep<<<dim3(360), dim3(256), 0, stream>>>(
        W_key, W_val, view_loc, view_lscl, noise_view,
        ao_loc, ao_scl, noise_obj, ab_loc, ab_scl, noise_bck,
        Wt, qbf, sview, sattr);
    k_lnkv<<<dim3(2048), dim3(256), 0, stream>>>(x, ln_in_g, ln_in_b, Wt, xkv);

    for (int it = 0; it < 3; ++it) {
        k_qry<<<dim3(224), dim3(192), 0, stream>>>(sview, sattr, ln_qry_g, ln_qry_b, W_qry, fullb, qbf);
        k_attn<<<dim3(512), dim3(256), 0, stream>>>(qbf, xkv, wbuf);
        k_upd<<<dim3(512), dim3(192), 0, stream>>>(wbuf, xkv, pU, pZ);
        k_gru<<<dim3(224), dim3(576), 0, stream>>>(pU, pZ, fullb, gru_Wi, gru_Wh, gru_bi, gru_bh,
                                                   ln_res_g, ln_res_b, mlp_W1, mlp_b1, mlp_W2, mlp_b2, fnew);
        float* ov = (it == 2) ? (float*)d_out : sview;
        float* oa = (it == 2) ? ((float*)d_out) + 2048 : sattr;
        k_means<<<dim3(36), dim3(256), 0, stream>>>(fnew, ov, oa);
    }
}

// Round 9
// 271.801 us; speedup vs baseline: 1.3563x; 1.0346x over previous
//
#include <hip/hip_runtime.h>
#include <cstdint>
#include <cstddef>

// ---------------------------------------------------------------- types
typedef float  f32x4 __attribute__((ext_vector_type(4)));
typedef short  s16x8 __attribute__((ext_vector_type(8)));
typedef __bf16 bf16x8 __attribute__((ext_vector_type(8)));

static __device__ __forceinline__ f32x4 mfma16(s16x8 a, s16x8 b, f32x4 c) {
    return __builtin_amdgcn_mfma_f32_16x16x32_bf16(
        __builtin_bit_cast(bf16x8, a), __builtin_bit_cast(bf16x8, b), c, 0, 0, 0);
}

static __device__ __forceinline__ unsigned short f2bf(float f) {
    unsigned int u = __builtin_bit_cast(unsigned int, f);
    u = (u + 0x7fffu + ((u >> 16) & 1u)) >> 16;
    return (unsigned short)u;
}
static __device__ __forceinline__ float bf2f(unsigned short h) {
    unsigned int u = ((unsigned int)h) << 16;
    return __builtin_bit_cast(float, u);
}

#define COEF 0.08838834764831845f

// ---------------------------------------------------------------- prep (round-1 verbatim)
__global__ __launch_bounds__(256) void k_prep(
    const float* __restrict__ Wkey, const float* __restrict__ Wval,
    const float* __restrict__ vloc, const float* __restrict__ vlscl, const float* __restrict__ nview,
    const float* __restrict__ aoloc, const float* __restrict__ aoscl, const float* __restrict__ nobj,
    const float* __restrict__ abloc, const float* __restrict__ abscl, const float* __restrict__ nbck,
    unsigned short* __restrict__ Wt, unsigned short* __restrict__ qbf,
    float* __restrict__ sview, float* __restrict__ sattr)
{
    int blk = blockIdx.x, t = threadIdx.x;
    if (blk < 320) {
        float v = (blk < 128) ? Wkey[t * 128 + blk] : Wval[t * 192 + (blk - 128)];
        Wt[blk * 256 + t] = f2bf(v);
    } else if (blk < 356) {
        int g = (blk - 320) * 256 + t;
        if (g < 2048) {
            int d = g & 63;
            sview[g] = vloc[d] + __expf(vlscl[d]) * nview[g];
        } else {
            int u = g - 2048;               // [b][s][128]
            int b = u / 896, r = u % 896, s = r >> 7, d = r & 127;
            float val;
            if (s < 6) val = aoloc[d] + __expf(aoscl[d]) * nobj[(b * 6 + s) * 128 + d];
            else       val = abloc[d] + __expf(abscl[d]) * nbck[b * 128 + d];
            sattr[u] = val;
        }
    } else {
        for (int e = (blk - 356) * 256 + t; e < 32 * 9 * 128; e += 1024) {
            int bv = e / 1152, r = e % 1152, s = 7 + r / 128, k = r & 127;
            qbf[(bv * 16 + s) * 128 + k] = 0;
        }
    }
}

// ---------------------------------------------------------------- phase A (round-1 verbatim, measured 110.8 us)
__global__ __launch_bounds__(256) void k_lnkv(
    const float* __restrict__ x, const float* __restrict__ lng, const float* __restrict__ lnb,
    const unsigned short* __restrict__ Wt, unsigned short* __restrict__ xkv)
{
    __shared__ unsigned short lds[64 * 320];        // 40 KB
    const int t = threadIdx.x, wave = t >> 6, lane = t & 63;
    const int l15 = lane & 15, lg = lane >> 4;
    const long rowbase = (long)blockIdx.x * 64;

    float4 gv = *(const float4*)(lng + lane * 4);
    float4 bv = *(const float4*)(lnb + lane * 4);
    for (int r = 0; r < 16; ++r) {
        int row = wave * 16 + r;
        float4 xv = *(const float4*)(x + (rowbase + row) * 256 + lane * 4);
        float s1 = xv.x + xv.y + xv.z + xv.w;
        float s2 = xv.x * xv.x + xv.y * xv.y + xv.z * xv.z + xv.w * xv.w;
        #pragma unroll
        for (int o = 32; o > 0; o >>= 1) { s1 += __shfl_xor(s1, o); s2 += __shfl_xor(s2, o); }
        float mean = s1 * (1.f / 256.f);
        float var  = s2 * (1.f / 256.f) - mean * mean;
        float rstd = rsqrtf(var + 1e-5f);
        float y0 = (xv.x - mean) * rstd * gv.x + bv.x;
        float y1 = (xv.y - mean) * rstd * gv.y + bv.y;
        float y2 = (xv.z - mean) * rstd * gv.z + bv.z;
        float y3 = (xv.w - mean) * rstd * gv.w + bv.w;
        unsigned int u0 = (unsigned)f2bf(y0) | ((unsigned)f2bf(y1) << 16);
        unsigned int u1 = (unsigned)f2bf(y2) | ((unsigned)f2bf(y3) << 16);
        int off = row * 512 + ((lane * 8) ^ ((row & 7) << 4));
        *(uint2*)((char*)lds + off) = make_uint2(u0, u1);
    }
    __syncthreads();

    f32x4 acc[4][5];
    #pragma unroll
    for (int mt = 0; mt < 4; ++mt)
        #pragma unroll
        for (int nt = 0; nt < 5; ++nt) acc[mt][nt] = (f32x4){0.f, 0.f, 0.f, 0.f};

    const int nb = wave * 80;
    #pragma unroll
    for (int kk = 0; kk < 8; ++kk) {
        s16x8 a[4], b[5];
        #pragma unroll
        for (int mt = 0; mt < 4; ++mt) {
            int row = mt * 16 + l15;
            int off = row * 512 + ((kk * 64 + lg * 16) ^ ((row & 7) << 4));
            a[mt] = *(const s16x8*)((char*)lds + off);
        }
        #pragma unroll
        for (int nt = 0; nt < 5; ++nt) {
            int col = nb + nt * 16 + l15;
            b[nt] = *(const s16x8*)(Wt + col * 256 + kk * 32 + lg * 8);
        }
        #pragma unroll
        for (int mt = 0; mt < 4; ++mt)
            #pragma unroll
            for (int nt = 0; nt < 5; ++nt)
                acc[mt][nt] = mfma16(a[mt], b[nt], acc[mt][nt]);
    }
    __syncthreads();

    #pragma unroll
    for (int mt = 0; mt < 4; ++mt)
        #pragma unroll
        for (int nt = 0; nt < 5; ++nt)
            #pragma unroll
            for (int rg = 0; rg < 4; ++rg) {
                int row = mt * 16 + lg * 4 + rg;
                int col = nb + nt * 16 + l15;
                lds[row * 320 + col] = f2bf(acc[mt][nt][rg]);
            }
    __syncthreads();
    const uint4* src = (const uint4*)lds;
    uint4* dst = (uint4*)(xkv + rowbase * 320);
    #pragma unroll
    for (int j = 0; j < 10; ++j) dst[j * 256 + t] = src[j * 256 + t];
}

// ---------------------------------------------------------------- per-iter: q v2 — 384 threads, 3-way k-split
__global__ __launch_bounds__(384) void k_qry(
    const float* __restrict__ sview, const float* __restrict__ sattr,
    const float* __restrict__ lng, const float* __restrict__ lnb,
    const float* __restrict__ Wq, float* __restrict__ full, unsigned short* __restrict__ qbf)
{
    int row = blockIdx.x;                  // bv*7 + s
    int bv = row / 7, s = row % 7, b = bv >> 2;
    int j = threadIdx.x;
    __shared__ float fr[192];
    __shared__ float part[384];
    __shared__ float red[8];
    float v = 0.f;
    if (j < 192) {
        v = (j < 64) ? sview[bv * 64 + j] : sattr[(b * 7 + s) * 128 + (j - 64)];
        full[row * 192 + j] = v;
        float s1 = v, s2 = v * v;
        #pragma unroll
        for (int o = 32; o > 0; o >>= 1) { s1 += __shfl_xor(s1, o); s2 += __shfl_xor(s2, o); }
        int wave = j >> 6, lane = j & 63;
        if (lane == 0) { red[wave] = s1; red[4 + wave] = s2; }
    }
    __syncthreads();
    if (j < 192) {
        float ts = red[0] + red[1] + red[2], ts2 = red[4] + red[5] + red[6];
        float mean = ts * (1.f / 192.f);
        float var  = ts2 * (1.f / 192.f) - mean * mean;
        float rstd = rsqrtf(var + 1e-5f);
        fr[j] = (v - mean) * rstd * lng[j] + lnb[j];
    }
    __syncthreads();
    {
        int c = j & 127, seg = j >> 7;               // 3 segments x 64 k
        float acc = 0.f;
        #pragma unroll
        for (int k = 0; k < 64; ++k) acc += fr[seg * 64 + k] * Wq[(seg * 64 + k) * 128 + c];
        part[j] = acc;
    }
    __syncthreads();
    if (j < 128) {
        float acc = part[j] + part[128 + j] + part[256 + j];
        qbf[(bv * 16 + s) * 128 + j] = f2bf(acc * COEF);
    }
}

// ---------------------------------------------------------------- per-iter: attn weights v2 — 1024 blocks (128-n chunks)
__global__ __launch_bounds__(256) void k_attn(
    const unsigned short* __restrict__ qbf, const unsigned short* __restrict__ xkv,
    float* __restrict__ wbuf)
{
    int blk = blockIdx.x;                  // 1024 = 32 bv * 32 chunks(128 n)
    int bv = blk >> 5, chunk = blk & 31;
    int t = threadIdx.x, wave = t >> 6, lane = t & 63;
    int l15 = lane & 15, lg = lane >> 4;

    s16x8 aq[4];
    const unsigned short* qrow = qbf + (bv * 16 + l15) * 128 + lg * 8;
    #pragma unroll
    for (int kk = 0; kk < 4; ++kk) aq[kk] = *(const s16x8*)(qrow + kk * 32);

    #pragma unroll
    for (int tt = 0; tt < 2; ++tt) {
        int ntb = chunk * 128 + (wave * 2 + tt) * 16;
        const unsigned short* xr = xkv + ((long)(bv * 4096 + ntb + l15)) * 320 + lg * 8;
        f32x4 acc = (f32x4){0.f, 0.f, 0.f, 0.f};
        #pragma unroll
        for (int kk = 0; kk < 4; ++kk) {
            s16x8 bfr = *(const s16x8*)(xr + kk * 32);
            acc = mfma16(aq[kk], bfr, acc);
        }
        float o0 = __shfl_xor(acc[0], 16), o1 = __shfl_xor(acc[1], 16);
        float o2 = __shfl_xor(acc[2], 16), o3 = __shfl_xor(acc[3], 16);
        bool hi = (lg & 1);
        float v0 = hi ? o0 : acc[0], v1 = hi ? o1 : acc[1];
        float v2 = hi ? o2 : acc[2], v3 = hi ? o3 : acc[3];
        float v4 = hi ? acc[0] : o0, v5 = hi ? acc[1] : o1, v6 = hi ? acc[2] : o2;
        float m = fmaxf(fmaxf(fmaxf(v0, v1), fmaxf(v2, v3)), fmaxf(fmaxf(v4, v5), v6));
        float e0 = __expf(v0 - m), e1 = __expf(v1 - m), e2 = __expf(v2 - m), e3 = __expf(v3 - m);
        float e4 = __expf(v4 - m), e5 = __expf(v5 - m), e6 = __expf(v6 - m);
        float inv = 1.f / (e0 + e1 + e2 + e3 + e4 + e5 + e6);
        if (lg < 2) {
            int n = ntb + l15;
            float4 out = (lg == 0) ? make_float4(e0 * inv, e1 * inv, e2 * inv, e3 * inv)
                                   : make_float4(e4 * inv, e5 * inv, e6 * inv, 0.f);
            *(float4*)(wbuf + ((long)(bv * 4096 + n)) * 8 + lg * 4) = out;
        }
    }
}

// ---------------------------------------------------------------- per-iter: updates partials v2 — 2048 blocks (64-n chunks)
// FIX r8: pZ reduce now fits 192 threads (t<112: s=t>>4 covers all 7 slots)
__global__ __launch_bounds__(192) void k_upd(
    const float* __restrict__ wbuf, const unsigned short* __restrict__ xkv,
    float* __restrict__ pU, float* __restrict__ pZ)
{
    int blk = blockIdx.x;                  // 2048 = 32 bv * 64 chunks(64 n)
    int bv = blk >> 6, chunk = blk & 63;
    int n0 = chunk * 64;
    int t = threadIdx.x;
    __shared__ float wl[64 * 8];
    for (int idx = t; idx < 512; idx += 192)
        wl[idx] = wbuf[((long)(bv * 4096 + n0)) * 8 + idx];
    __syncthreads();
    float a0 = 0, a1 = 0, a2 = 0, a3 = 0, a4 = 0, a5 = 0, a6 = 0;
    const unsigned short* xp = xkv + ((long)(bv * 4096 + n0)) * 320 + 128 + t;
    #pragma unroll 4
    for (int n = 0; n < 64; ++n) {
        float xv = bf2f(xp[n * 320]);
        float4 wa = *(const float4*)(wl + n * 8);
        float4 wb = *(const float4*)(wl + n * 8 + 4);
        a0 += wa.x * xv; a1 += wa.y * xv; a2 += wa.z * xv; a3 += wa.w * xv;
        a4 += wb.x * xv; a5 += wb.y * xv; a6 += wb.z * xv;
    }
    long base = (((long)bv * 64 + chunk) * 7) * 192 + t;
    pU[base + 0 * 192] = a0; pU[base + 1 * 192] = a1; pU[base + 2 * 192] = a2;
    pU[base + 3 * 192] = a3; pU[base + 4 * 192] = a4; pU[base + 5 * 192] = a5;
    pU[base + 6 * 192] = a6;
    if (t < 112) {
        int s = t >> 4, part = t & 15;               // s = 0..6, 16 lanes each
        float z = 0.f;
        #pragma unroll
        for (int k = 0; k < 4; ++k) z += wl[(part + 16 * k) * 8 + s];
        #pragma unroll
        for (int o = 8; o > 0; o >>= 1) z += __shfl_xor(z, o);   // stays in 16-lane group
        if (part == 0) pZ[(bv * 64 + chunk) * 7 + s] = z;
    }
}

// ---------------------------------------------------------------- per-iter: GRU+MLP (r7 gate-parallel; 64-chunk reduce)
__global__ __launch_bounds__(576) void k_gru(
    const float* __restrict__ pU, const float* __restrict__ pZ, const float* __restrict__ full,
    const float* __restrict__ Wi, const float* __restrict__ Wh,
    const float* __restrict__ bi, const float* __restrict__ bh,
    const float* __restrict__ lng, const float* __restrict__ lnb,
    const float* __restrict__ W1, const float* __restrict__ b1,
    const float* __restrict__ W2, const float* __restrict__ b2,
    float* __restrict__ fnew)
{
    int row = blockIdx.x;                  // bv*7 + s
    int bv = row / 7, s = row % 7;
    int j = threadIdx.x;
    __shared__ float u[192], h[192], gi[576], gh[576], lnm[192], h1[256], red[8];

    // ---- phase 1: u (pU/Z reduce over 64 chunks) and h
    if (j < 192) {
        float us = 0.f;
        #pragma unroll 8
        for (int c = 0; c < 64; ++c) us += pU[(((long)bv * 64 + c) * 7 + s) * 192 + j];
        float Z = 0.f;
        #pragma unroll 8
        for (int c = 0; c < 64; ++c) Z += pZ[(bv * 64 + c) * 7 + s];
        u[j] = us / Z;
    } else if (j < 384) {
        int jj = j - 192;
        h[jj] = full[row * 192 + jj];
    }
    __syncthreads();

    // ---- phase 2: one gate column per thread
    {
        float a = 0.f, b = 0.f;
        for (int k = 0; k < 192; ++k) {
            a += u[k] * Wi[k * 576 + j];
            b += h[k] * Wh[k * 576 + j];
        }
        gi[j] = a + bi[j];
        gh[j] = b + bh[j];
    }
    __syncthreads();

    // ---- phase 3: gates + GRU combine + LN (threads 0..191)
    float mn = 0.f;
    if (j < 192) {
        float hv = h[j];
        float r  = 1.f / (1.f + __expf(-(gi[j] + gh[j])));
        float z  = 1.f / (1.f + __expf(-(gi[192 + j] + gh[192 + j])));
        float nn = tanhf(gi[384 + j] + r * gh[384 + j]);
        mn = (1.f - z) * nn + z * hv;

        float s1 = mn, s2 = mn * mn;
        #pragma unroll
        for (int o = 32; o > 0; o >>= 1) { s1 += __shfl_xor(s1, o); s2 += __shfl_xor(s2, o); }
        int wave = j >> 6, lane = j & 63;
        if (lane == 0) { red[wave] = s1; red[4 + wave] = s2; }
    }
    __syncthreads();
    if (j < 192) {
        float ts = red[0] + red[1] + red[2], ts2 = red[4] + red[5] + red[6];
        float mean = ts * (1.f / 192.f);
        float var  = ts2 * (1.f / 192.f) - mean * mean;
        float rstd = rsqrtf(var + 1e-5f);
        lnm[j] = (mn - mean) * rstd * lng[j] + lnb[j];
    }
    __syncthreads();

    // ---- phase 4: MLP hidden (threads 0..255)
    if (j < 256) {
        float acc = 0.f;
        for (int k = 0; k < 192; ++k) acc += lnm[k] * W1[k * 256 + j];
        h1[j] = fmaxf(acc + b1[j], 0.f);
    }
    __syncthreads();

    // ---- phase 5: MLP out + residual (threads 0..191)
    if (j < 192) {
        float resj = b2[j];
        for (int c = 0; c < 256; ++c) resj += h1[c] * W2[c * 192 + j];
        fnew[row * 192 + j] = mn + resj;
    }
}

// ---------------------------------------------------------------- per-iter: slot means (round-1 verbatim)
__global__ __launch_bounds__(256) void k_means(
    const float* __restrict__ fnew, float* __restrict__ oview, float* __restrict__ oattr)
{
    int t = blockIdx.x * 256 + threadIdx.x;
    if (t < 2048) {
        int bv = t >> 6, d = t & 63;
        float a = 0.f;
        #pragma unroll
        for (int s = 0; s < 7; ++s) a += fnew[(bv * 7 + s) * 192 + d];
        oview[t] = a * (1.f / 7.f);
    } else if (t < 9216) {
        int u = t - 2048;
        int b = u / 896, r = u % 896, s = r >> 7, d = r & 127;
        float a = 0.f;
        #pragma unroll
        for (int v = 0; v < 4; ++v) a += fnew[((b * 4 + v) * 7 + s) * 192 + 64 + d];
        oattr[u] = a * 0.25f;
    }
}

// ---------------------------------------------------------------- host
extern "C" void kernel_launch(void* const* d_in, const int* in_sizes, int n_in,
                              void* d_out, int out_size, void* d_ws, size_t ws_size,
                              hipStream_t stream)
{
    const float* x          = (const float*)d_in[0];
    const float* noise_view = (const float*)d_in[1];
    const float* noise_obj  = (const float*)d_in[2];
    const float* noise_bck  = (const float*)d_in[3];
    const float* ln_in_g    = (const float*)d_in[4];
    const float* ln_in_b    = (const float*)d_in[5];
    const float* ln_qry_g   = (const float*)d_in[6];
    const float* ln_qry_b   = (const float*)d_in[7];
    const float* ln_res_g   = (const float*)d_in[8];
    const float* ln_res_b   = (const float*)d_in[9];
    const float* view_loc   = (const float*)d_in[10];
    const float* view_lscl  = (const float*)d_in[11];
    const float* ao_loc     = (const float*)d_in[12];
    const float* ao_scl     = (const float*)d_in[13];
    const float* ab_loc     = (const float*)d_in[14];
    const float* ab_scl     = (const float*)d_in[15];
    const float* W_qry      = (const float*)d_in[16];
    const float* W_key      = (const float*)d_in[17];
    const float* W_val      = (const float*)d_in[18];
    const float* gru_Wi     = (const float*)d_in[19];
    const float* gru_Wh     = (const float*)d_in[20];
    const float* gru_bi     = (const float*)d_in[21];
    const float* gru_bh     = (const float*)d_in[22];
    const float* mlp_W1     = (const float*)d_in[23];
    const float* mlp_b1     = (const float*)d_in[24];
    const float* mlp_W2     = (const float*)d_in[25];
    const float* mlp_b2     = (const float*)d_in[26];

    char* ws = (char*)d_ws;
    size_t off = 0;
    auto alloc = [&](size_t bytes) { void* p = ws + off; off += (bytes + 255) & ~255ULL; return p; };
    unsigned short* xkv = (unsigned short*)alloc(131072UL * 320 * 2);   // 80 MB
    unsigned short* Wt  = (unsigned short*)alloc(320UL * 256 * 2);
    unsigned short* qbf = (unsigned short*)alloc(32UL * 16 * 128 * 2);
    float* wbuf  = (float*)alloc(32UL * 4096 * 8 * 4);                  // 4 MB
    float* pU    = (float*)alloc(32UL * 64 * 7 * 192 * 4);              // 11 MB
    float* pZ    = (float*)alloc(32UL * 64 * 7 * 4);
    float* fullb = (float*)alloc(224UL * 192 * 4);
    float* fnew  = (float*)alloc(224UL * 192 * 4);
    float* sview = (float*)alloc(2048UL * 4);
    float* sattr = (float*)alloc(7168UL * 4);

    k_prep<<<dim3(360), dim3(256), 0, stream>>>(
        W_key, W_val, view_loc, view_lscl, noise_view,
        ao_loc, ao_scl, noise_obj, ab_loc, ab_scl, noise_bck,
        Wt, qbf, sview, sattr);
    k_lnkv<<<dim3(2048), dim3(256), 0, stream>>>(x, ln_in_g, ln_in_b, Wt, xkv);

    for (int it = 0; it < 3; ++it) {
        k_qry<<<dim3(224), dim3(384), 0, stream>>>(sview, sattr, ln_qry_g, ln_qry_b, W_qry, fullb, qbf);
        k_attn<<<dim3(1024), dim3(256), 0, stream>>>(qbf, xkv, wbuf);
        k_upd<<<dim3(2048), dim3(192), 0, stream>>>(wbuf, xkv, pU, pZ);
        k_gru<<<dim3(224), dim3(576), 0, stream>>>(pU, pZ, fullb, gru_Wi, gru_Wh, gru_bi, gru_bh,
                                                   ln_res_g, ln_res_b, mlp_W1, mlp_b1, mlp_W2, mlp_b2, fnew);
        float* ov = (it == 2) ? (float*)d_out : sview;
        float* oa = (it == 2) ? ((float*)d_out) + 2048 : sattr;
        k_means<<<dim3(36), dim3(256), 0, stream>>>(fnew, ov, oa);
    }
}